// Round 11
// baseline (373.843 us; speedup 1.0000x reference)
//
#include <hip/hip_runtime.h>

#define HID 64
#define CH 256       // edge chunks (= k_cfill grid)
#define MAXNB 800    // LDS bucket-counter capacity (>= runtime nb = 782)
#define MAXCE 6400   // LDS chunk-sort capacity (>= runtime ce = 6250)
#define CAP 4096     // LDS bucket-stage capacity (>= max bucket size ~2300)

// ---------------- CSR build: chunk-local counting sort ----------------

__global__ __launch_bounds__(256) void k_cfill(
        const int* __restrict__ src, const int* __restrict__ dst,
        int* __restrict__ counts, int* __restrict__ loff,
        int* __restrict__ colsum, int* __restrict__ tmp,
        int E, int ce, int nb) {
    __shared__ int lcnt[MAXNB];
    __shared__ int lscan[MAXNB];
    __shared__ int sums[256];
    __shared__ int sorted[MAXCE];
    const int c = blockIdx.x;
    const int t = threadIdx.x;
    for (int j = t; j < nb; j += 256) lcnt[j] = 0;
    __syncthreads();
    const int s0 = c * ce, e0 = min(s0 + ce, E);
    for (int i = s0 + t; i < e0; i += 256) atomicAdd(&lcnt[dst[i] >> 7], 1);
    __syncthreads();
    for (int j = t; j < nb; j += 256) {
        int v = lcnt[j];
        counts[(size_t)c * nb + j] = v;
        if (v) atomicAdd(&colsum[j], v);
    }
    const int per = (nb + 255) >> 8;
    const int base = t * per;
    int vals[8];
    int s = 0;
    for (int k = 0; k < per; k++) {
        int f = base + k;
        int v = (f < nb) ? lcnt[f] : 0;
        vals[k] = s;
        s += v;
    }
    sums[t] = s;
    __syncthreads();
    for (int ofs = 1; ofs < 256; ofs <<= 1) {
        int v = (t >= ofs) ? sums[t - ofs] : 0;
        __syncthreads();
        sums[t] += v;
        __syncthreads();
    }
    const int carry = (t > 0) ? sums[t - 1] : 0;
    for (int k = 0; k < per; k++) {
        int f = base + k;
        if (f < nb) {
            int ex = carry + vals[k];
            lscan[f] = ex;
            loff[(size_t)c * nb + f] = ex;
        }
    }
    __syncthreads();
    for (int i = s0 + t; i < e0; i += 256) {
        int d = dst[i];
        int sv = src[i];
        int p = atomicAdd(&lscan[d >> 7], 1);
        sorted[p] = sv | ((d & 127) << 17);
    }
    __syncthreads();
    const int n = e0 - s0;
    for (int j = t; j < n; j += 256) tmp[s0 + j] = sorted[j];
}

__global__ __launch_bounds__(1024) void k_bbase(
        const int* __restrict__ colsum, int* __restrict__ bucket_base,
        int* __restrict__ row_start, int N, int E, int nb) {
    __shared__ int sums[1024];
    const int t = threadIdx.x;
    int v = (t < nb) ? colsum[t] : 0;
    sums[t] = v;
    __syncthreads();
    for (int ofs = 1; ofs < 1024; ofs <<= 1) {
        int u = (t >= ofs) ? sums[t - ofs] : 0;
        __syncthreads();
        sums[t] += u;
        __syncthreads();
    }
    if (t < nb) bucket_base[t] = sums[t] - v;
    if (t == 0) { bucket_base[nb] = E; row_start[N] = E; }
}

__global__ __launch_bounds__(256) void k_pass2(
        const int* __restrict__ tmp, const int* __restrict__ counts,
        const int* __restrict__ loff, const int* __restrict__ bucket_base,
        int* __restrict__ col, int* __restrict__ row_start,
        float* __restrict__ dis, int N, int ce, int nb) {
    __shared__ int stage[CAP];
    __shared__ int soff[256];
    __shared__ int lcnt[128];
    __shared__ int lofs[128];
    const int b = blockIdx.x;
    const int t = threadIdx.x;
    const int cnt = counts[(size_t)t * nb + b];
    const int lo  = loff[(size_t)t * nb + b];
    soff[t] = cnt;
    __syncthreads();
    for (int ofs = 1; ofs < 256; ofs <<= 1) {
        int v = (t >= ofs) ? soff[t - ofs] : 0;
        __syncthreads();
        soff[t] += v;
        __syncthreads();
    }
    const int total = soff[255];
    const int my0 = soff[t] - cnt;
    for (int k = 0; k < cnt; k++) stage[my0 + k] = tmp[t * ce + lo + k];
    if (t < 128) lcnt[t] = 0;
    __syncthreads();
    for (int i = t; i < total; i += 256) atomicAdd(&lcnt[(stage[i] >> 17) & 127], 1);
    __syncthreads();
    if (t < 128) lofs[t] = lcnt[t];
    __syncthreads();
    for (int ofs = 1; ofs < 128; ofs <<= 1) {
        int v = (t < 128 && t >= ofs) ? lofs[t - ofs] : 0;
        __syncthreads();
        if (t < 128) lofs[t] += v;
        __syncthreads();
    }
    const int base = bucket_base[b];
    if (t < 128) {
        int node = (b << 7) + t;
        int ex = lofs[t] - lcnt[t];
        if (node < N) {
            row_start[node] = base + ex;
            dis[node] = rsqrtf((float)(lcnt[t] + 1));
        }
        lcnt[t] = ex;
    }
    __syncthreads();
    for (int i = t; i < total; i += 256) {
        int v = stage[i];
        int d = (v >> 17) & 127;
        int p = atomicAdd(&lcnt[d], 1);
        col[base + p] = v & 0x1FFFF;
    }
}

// ---------------- per-layer compute ----------------

// hw[n,f] = (X[n,:] @ W[:,f]) * dis[n], stored as bf16 (RNE).
__global__ __launch_bounds__(256) void k_gemm_scale(
        const float* __restrict__ X, const float* __restrict__ W,
        const float* __restrict__ dis, unsigned short* __restrict__ out, int N) {
    __shared__ float xsh[4][64];
    const int wave = threadIdx.x >> 6;
    const int lane = threadIdx.x & 63;
    float wcol[64];
#pragma unroll
    for (int k = 0; k < 64; k++) wcol[k] = W[k * 64 + lane];

    const int nwaves = gridDim.x * 4;
    for (int node = blockIdx.x * 4 + wave; node < N; node += nwaves) {
        xsh[wave][lane] = X[(size_t)node * 64 + lane];
        asm volatile("s_waitcnt lgkmcnt(0)" ::: "memory");
        float acc = 0.f;
#pragma unroll
        for (int k = 0; k < 64; k += 4) {
            float4 xv = *(const float4*)&xsh[wave][k];
            acc += xv.x * wcol[k]     + xv.y * wcol[k + 1]
                 + xv.z * wcol[k + 2] + xv.w * wcol[k + 3];
        }
        unsigned u = __float_as_uint(acc * dis[node]);
        u += 0x7fffu + ((u >> 16) & 1u);   // RNE to bf16
        out[(size_t)node * 64 + lane] = (unsigned short)(u >> 16);
    }
}

__device__ __forceinline__ float4 bf4_to_f4(uint2 v) {
    float4 r;
    r.x = __uint_as_float(v.x << 16);
    r.y = __uint_as_float(v.x & 0xffff0000u);
    r.z = __uint_as_float(v.y << 16);
    r.w = __uint_as_float(v.y & 0xffff0000u);
    return r;
}

// h[n,f] = relu( dis[n] * ( hw[n,f] + sum_{e} hw[col[e],f] ) + b[f] ), hw bf16.
// quarter q = lane>>4 handles edges j+q, j+q+4, ...; t = lane&15 owns features
// 4t..4t+3 (uint2 = 4 bf16, 8 B/lane). Unroll x8 -> 4 KB in flight per wave.
__global__ __launch_bounds__(256) void k_gather(
        const unsigned short* __restrict__ hw, const int* __restrict__ row_start,
        const int* __restrict__ col, const float* __restrict__ dis,
        const float* __restrict__ bias, float* __restrict__ out, int N) {
    const int wave = threadIdx.x >> 6;
    const int lane = threadIdx.x & 63;
    const int q = lane >> 4;
    const int t = lane & 15;
    const float4 b4 = *(const float4*)&bias[4 * t];
    const int nwaves = gridDim.x * 4;
    for (int node = blockIdx.x * 4 + wave; node < N; node += nwaves) {
        int s = row_start[node];
        int e = row_start[node + 1];
        float4 acc;
        if (q == 0) {
            acc = bf4_to_f4(*(const uint2*)&hw[(size_t)node * 64 + 4 * t]);  // self loop
        } else {
            acc.x = 0.f; acc.y = 0.f; acc.z = 0.f; acc.w = 0.f;
        }
        int j = s + q;
        for (; j + 28 < e; j += 32) {
            int c0 = __builtin_nontemporal_load(&col[j]);
            int c1 = __builtin_nontemporal_load(&col[j + 4]);
            int c2 = __builtin_nontemporal_load(&col[j + 8]);
            int c3 = __builtin_nontemporal_load(&col[j + 12]);
            int c4 = __builtin_nontemporal_load(&col[j + 16]);
            int c5 = __builtin_nontemporal_load(&col[j + 20]);
            int c6 = __builtin_nontemporal_load(&col[j + 24]);
            int c7 = __builtin_nontemporal_load(&col[j + 28]);
            const uint2 w0 = *(const uint2*)&hw[(size_t)c0 * 64 + 4 * t];
            const uint2 w1 = *(const uint2*)&hw[(size_t)c1 * 64 + 4 * t];
            const uint2 w2 = *(const uint2*)&hw[(size_t)c2 * 64 + 4 * t];
            const uint2 w3 = *(const uint2*)&hw[(size_t)c3 * 64 + 4 * t];
            const uint2 w4 = *(const uint2*)&hw[(size_t)c4 * 64 + 4 * t];
            const uint2 w5 = *(const uint2*)&hw[(size_t)c5 * 64 + 4 * t];
            const uint2 w6 = *(const uint2*)&hw[(size_t)c6 * 64 + 4 * t];
            const uint2 w7 = *(const uint2*)&hw[(size_t)c7 * 64 + 4 * t];
            float4 v;
            v = bf4_to_f4(w0); acc.x += v.x; acc.y += v.y; acc.z += v.z; acc.w += v.w;
            v = bf4_to_f4(w1); acc.x += v.x; acc.y += v.y; acc.z += v.z; acc.w += v.w;
            v = bf4_to_f4(w2); acc.x += v.x; acc.y += v.y; acc.z += v.z; acc.w += v.w;
            v = bf4_to_f4(w3); acc.x += v.x; acc.y += v.y; acc.z += v.z; acc.w += v.w;
            v = bf4_to_f4(w4); acc.x += v.x; acc.y += v.y; acc.z += v.z; acc.w += v.w;
            v = bf4_to_f4(w5); acc.x += v.x; acc.y += v.y; acc.z += v.z; acc.w += v.w;
            v = bf4_to_f4(w6); acc.x += v.x; acc.y += v.y; acc.z += v.z; acc.w += v.w;
            v = bf4_to_f4(w7); acc.x += v.x; acc.y += v.y; acc.z += v.z; acc.w += v.w;
        }
        for (; j < e; j += 4) {
            int c = __builtin_nontemporal_load(&col[j]);
            float4 v = bf4_to_f4(*(const uint2*)&hw[(size_t)c * 64 + 4 * t]);
            acc.x += v.x; acc.y += v.y; acc.z += v.z; acc.w += v.w;
        }
        acc.x += __shfl_xor(acc.x, 16); acc.y += __shfl_xor(acc.y, 16);
        acc.z += __shfl_xor(acc.z, 16); acc.w += __shfl_xor(acc.w, 16);
        acc.x += __shfl_xor(acc.x, 32); acc.y += __shfl_xor(acc.y, 32);
        acc.z += __shfl_xor(acc.z, 32); acc.w += __shfl_xor(acc.w, 32);
        if (q == 0) {
            float d = dis[node];
            float4 r;
            r.x = fmaxf(acc.x * d + b4.x, 0.f);
            r.y = fmaxf(acc.y * d + b4.y, 0.f);
            r.z = fmaxf(acc.z * d + b4.z, 0.f);
            r.w = fmaxf(acc.w * d + b4.w, 0.f);
            *(float4*)&out[(size_t)node * 64 + 4 * t] = r;
        }
    }
}

// ---------------- pool + MLP ----------------

__global__ __launch_bounds__(256) void k_pool(
        const float* __restrict__ h, const int* __restrict__ batch,
        int N, float* __restrict__ pooled) {
    __shared__ float part[4][64];
    const int g = blockIdx.x;
    const int w = threadIdx.x >> 6;
    const int lane = threadIdx.x & 63;
    int lo = 0, hi = N;
    while (lo < hi) { int mid = (lo + hi) >> 1; if (batch[mid] < g) lo = mid + 1; else hi = mid; }
    int s = lo;
    lo = 0; hi = N;
    while (lo < hi) { int mid = (lo + hi) >> 1; if (batch[mid] < g + 1) lo = mid + 1; else hi = mid; }
    int e = lo;
    float acc = 0.f;
    for (int i = s + w; i < e; i += 4) acc += h[(size_t)i * 64 + lane];
    part[w][lane] = acc;
    __syncthreads();
    if (w == 0) {
        float v = part[0][lane] + part[1][lane] + part[2][lane] + part[3][lane];
        float cnt = (float)(e - s);
        pooled[(size_t)g * 64 + lane] = v / fmaxf(cnt, 1.f);
    }
}

__global__ void k_mlp(const float* __restrict__ pooled, const float* __restrict__ Wc1,
                      const float* __restrict__ bc1, const float* __restrict__ Wc2,
                      const float* __restrict__ bc2, float* __restrict__ out) {
    __shared__ float sh[64];
    const int g = blockIdx.x;
    const int t = threadIdx.x;
    sh[t] = pooled[(size_t)g * 64 + t];
    __syncthreads();
    float part = 0.f;
    if (t < 32) {
        float z = bc1[t];
#pragma unroll
        for (int f = 0; f < 64; f++) z += sh[f] * Wc1[f * 32 + t];
        z = fmaxf(z, 0.f);
        part = z * Wc2[t];
    }
    for (int ofs = 32; ofs > 0; ofs >>= 1) part += __shfl_down(part, ofs);
    if (t == 0) out[g] = part + bc2[0];
}

// ---------------- launch ----------------

extern "C" void kernel_launch(void* const* d_in, const int* in_sizes, int n_in,
                              void* d_out, int out_size, void* d_ws, size_t ws_size,
                              hipStream_t stream) {
    const float* x     = (const float*)d_in[0];
    const int*   ei    = (const int*)d_in[1];
    const int*   batch = (const int*)d_in[2];
    const float* W1 = (const float*)d_in[3];  const float* b1 = (const float*)d_in[4];
    const float* W2 = (const float*)d_in[5];  const float* b2 = (const float*)d_in[6];
    const float* W3 = (const float*)d_in[7];  const float* b3 = (const float*)d_in[8];
    const float* Wc1 = (const float*)d_in[9];  const float* bc1 = (const float*)d_in[10];
    const float* Wc2 = (const float*)d_in[11]; const float* bc2 = (const float*)d_in[12];
    float* out = (float*)d_out;

    const int N = in_sizes[0] / 64;   // 100000
    const int E = in_sizes[1] / 2;    // 1600000
    const int G = out_size;           // 1024
    const int* src = ei;
    const int* dst = ei + E;
    const int nb = (N + 127) >> 7;    // 782 buckets
    const int ce = (E + CH - 1) / CH; // 6250 edges/chunk

    char* w = (char*)d_ws;
    auto alloc = [&](size_t bytes) -> void* {
        void* p = (void*)w;
        w += (bytes + 255) & ~(size_t)255;
        return p;
    };
    float* dis         = (float*)alloc((size_t)N * 4);
    int*   row_start   = (int*)alloc((size_t)(N + 1) * 4);
    int*   col         = (int*)alloc((size_t)E * 4);
    int*   counts      = (int*)alloc((size_t)CH * nb * 4);
    int*   loff        = (int*)alloc((size_t)CH * nb * 4);
    int*   colsum      = (int*)alloc((size_t)nb * 4);
    int*   bucket_base = (int*)alloc((size_t)(nb + 1) * 4);
    unsigned short* hwb = (unsigned short*)alloc((size_t)N * 64 * 2);  // bf16 hw
    float* hbuf        = (float*)alloc((size_t)N * 64 * 4);            // f32 h
    float* pooled      = (float*)alloc((size_t)G * 64 * 4);
    int*   tmp         = (int*)hbuf;  // alias: CSR build finishes before layer 1
    (void)ws_size; (void)n_in;

    hipMemsetAsync(colsum, 0, (size_t)nb * 4, stream);
    k_cfill<<<CH, 256, 0, stream>>>(src, dst, counts, loff, colsum, tmp, E, ce, nb);
    k_bbase<<<1, 1024, 0, stream>>>(colsum, bucket_base, row_start, N, E, nb);
    k_pass2<<<nb, 256, 0, stream>>>(tmp, counts, loff, bucket_base, col, row_start, dis, N, ce, nb);

    // layer 1
    k_gemm_scale<<<2048, 256, 0, stream>>>(x, W1, dis, hwb, N);
    k_gather<<<4096, 256, 0, stream>>>(hwb, row_start, col, dis, b1, hbuf, N);
    // layer 2
    k_gemm_scale<<<2048, 256, 0, stream>>>(hbuf, W2, dis, hwb, N);
    k_gather<<<4096, 256, 0, stream>>>(hwb, row_start, col, dis, b2, hbuf, N);
    // layer 3
    k_gemm_scale<<<2048, 256, 0, stream>>>(hbuf, W3, dis, hwb, N);
    k_gather<<<4096, 256, 0, stream>>>(hwb, row_start, col, dis, b3, hbuf, N);

    k_pool<<<G, 256, 0, stream>>>(hbuf, batch, N, pooled);
    k_mlp<<<G, 64, 0, stream>>>(pooled, Wc1, bc1, Wc2, bc2, out);
}

// Round 13
// 341.161 us; speedup vs baseline: 1.0958x; 1.0958x over previous
//
#include <hip/hip_runtime.h>

#define HID 64
#define CH 256       // edge chunks (= k_cfill grid)
#define MAXNB 800    // LDS bucket-counter capacity (>= runtime nb = 782)
#define MAXCE 6400   // LDS chunk-sort capacity (>= runtime ce = 6250)
#define CAP 4096     // LDS bucket-stage capacity (>= max bucket size ~2300)

// ---------------- CSR build: chunk-local counting sort ----------------

__global__ __launch_bounds__(256) void k_cfill(
        const int* __restrict__ src, const int* __restrict__ dst,
        int* __restrict__ counts, int* __restrict__ loff,
        int* __restrict__ colsum, int* __restrict__ tmp,
        int E, int ce, int nb) {
    __shared__ int lcnt[MAXNB];
    __shared__ int lscan[MAXNB];
    __shared__ int sums[256];
    __shared__ int sorted[MAXCE];
    const int c = blockIdx.x;
    const int t = threadIdx.x;
    for (int j = t; j < nb; j += 256) lcnt[j] = 0;
    __syncthreads();
    const int s0 = c * ce, e0 = min(s0 + ce, E);
    for (int i = s0 + t; i < e0; i += 256) atomicAdd(&lcnt[dst[i] >> 7], 1);
    __syncthreads();
    for (int j = t; j < nb; j += 256) {
        int v = lcnt[j];
        counts[(size_t)c * nb + j] = v;
        if (v) atomicAdd(&colsum[j], v);
    }
    const int per = (nb + 255) >> 8;
    const int base = t * per;
    int vals[8];
    int s = 0;
    for (int k = 0; k < per; k++) {
        int f = base + k;
        int v = (f < nb) ? lcnt[f] : 0;
        vals[k] = s;
        s += v;
    }
    sums[t] = s;
    __syncthreads();
    for (int ofs = 1; ofs < 256; ofs <<= 1) {
        int v = (t >= ofs) ? sums[t - ofs] : 0;
        __syncthreads();
        sums[t] += v;
        __syncthreads();
    }
    const int carry = (t > 0) ? sums[t - 1] : 0;
    for (int k = 0; k < per; k++) {
        int f = base + k;
        if (f < nb) {
            int ex = carry + vals[k];
            lscan[f] = ex;
            loff[(size_t)c * nb + f] = ex;
        }
    }
    __syncthreads();
    for (int i = s0 + t; i < e0; i += 256) {
        int d = dst[i];
        int sv = src[i];
        int p = atomicAdd(&lscan[d >> 7], 1);
        sorted[p] = sv | ((d & 127) << 17);
    }
    __syncthreads();
    const int n = e0 - s0;
    for (int j = t; j < n; j += 256) tmp[s0 + j] = sorted[j];
}

__global__ __launch_bounds__(1024) void k_bbase(
        const int* __restrict__ colsum, int* __restrict__ bucket_base,
        int* __restrict__ row_start, int N, int E, int nb) {
    __shared__ int sums[1024];
    const int t = threadIdx.x;
    int v = (t < nb) ? colsum[t] : 0;
    sums[t] = v;
    __syncthreads();
    for (int ofs = 1; ofs < 1024; ofs <<= 1) {
        int u = (t >= ofs) ? sums[t - ofs] : 0;
        __syncthreads();
        sums[t] += u;
        __syncthreads();
    }
    if (t < nb) bucket_base[t] = sums[t] - v;
    if (t == 0) { bucket_base[nb] = E; row_start[N] = E; }
}

__global__ __launch_bounds__(256) void k_pass2(
        const int* __restrict__ tmp, const int* __restrict__ counts,
        const int* __restrict__ loff, const int* __restrict__ bucket_base,
        int* __restrict__ col, int* __restrict__ row_start,
        float* __restrict__ dis, int N, int ce, int nb) {
    __shared__ int stage[CAP];
    __shared__ int soff[256];
    __shared__ int lcnt[128];
    __shared__ int lofs[128];
    const int b = blockIdx.x;
    const int t = threadIdx.x;
    const int cnt = counts[(size_t)t * nb + b];
    const int lo  = loff[(size_t)t * nb + b];
    soff[t] = cnt;
    __syncthreads();
    for (int ofs = 1; ofs < 256; ofs <<= 1) {
        int v = (t >= ofs) ? soff[t - ofs] : 0;
        __syncthreads();
        soff[t] += v;
        __syncthreads();
    }
    const int total = soff[255];
    const int my0 = soff[t] - cnt;
    for (int k = 0; k < cnt; k++) stage[my0 + k] = tmp[t * ce + lo + k];
    if (t < 128) lcnt[t] = 0;
    __syncthreads();
    for (int i = t; i < total; i += 256) atomicAdd(&lcnt[(stage[i] >> 17) & 127], 1);
    __syncthreads();
    if (t < 128) lofs[t] = lcnt[t];
    __syncthreads();
    for (int ofs = 1; ofs < 128; ofs <<= 1) {
        int v = (t < 128 && t >= ofs) ? lofs[t - ofs] : 0;
        __syncthreads();
        if (t < 128) lofs[t] += v;
        __syncthreads();
    }
    const int base = bucket_base[b];
    if (t < 128) {
        int node = (b << 7) + t;
        int ex = lofs[t] - lcnt[t];
        if (node < N) {
            row_start[node] = base + ex;
            dis[node] = rsqrtf((float)(lcnt[t] + 1));
        }
        lcnt[t] = ex;
    }
    __syncthreads();
    for (int i = t; i < total; i += 256) {
        int v = stage[i];
        int d = (v >> 17) & 127;
        int p = atomicAdd(&lcnt[d], 1);
        col[base + p] = v & 0x1FFFF;
    }
}

// ---------------- per-layer compute ----------------

// out[n,f] = (X[n,:] @ W[:,f]) * dis[n]  ; wcol held in VGPRs (1 KB LDS only)
__global__ __launch_bounds__(256) void k_gemm_scale(
        const float* __restrict__ X, const float* __restrict__ W,
        const float* __restrict__ dis, float* __restrict__ out, int N) {
    __shared__ float xsh[4][64];
    const int wave = threadIdx.x >> 6;
    const int lane = threadIdx.x & 63;
    float wcol[64];
#pragma unroll
    for (int k = 0; k < 64; k++) wcol[k] = W[k * 64 + lane];

    const int nwaves = gridDim.x * 4;
    for (int node = blockIdx.x * 4 + wave; node < N; node += nwaves) {
        xsh[wave][lane] = X[(size_t)node * 64 + lane];
        asm volatile("s_waitcnt lgkmcnt(0)" ::: "memory");
        float acc = 0.f;
#pragma unroll
        for (int k = 0; k < 64; k += 4) {
            float4 xv = *(const float4*)&xsh[wave][k];
            acc += xv.x * wcol[k]     + xv.y * wcol[k + 1]
                 + xv.z * wcol[k + 2] + xv.w * wcol[k + 3];
        }
        out[(size_t)node * 64 + lane] = acc * dis[node];
    }
}

// h[n,f] = relu( dis[n] * ( hw[n,f] + sum_{e} hw[col[e],f] ) + b[f] )
// One coalesced load pulls the node's col indices into lane registers; quarters
// receive indices via __shfl. ALL shfl sites execute with wave-uniform control
// flow (kk, dm wave-uniform) so no lane reads an exec-masked-off source (the
// R12 bug). Remainder uses clamped source lane + predicated accumulate.
__global__ __launch_bounds__(256) void k_gather(
        const float* __restrict__ hw, const int* __restrict__ row_start,
        const int* __restrict__ col, const float* __restrict__ dis,
        const float* __restrict__ bias, float* __restrict__ out, int N) {
    const int wave = threadIdx.x >> 6;
    const int lane = threadIdx.x & 63;
    const int q = lane >> 4;
    const int t = lane & 15;
    const float4 b4 = *(const float4*)&bias[4 * t];
    const int nwaves = gridDim.x * 4;
    for (int node = blockIdx.x * 4 + wave; node < N; node += nwaves) {
        const int s = row_start[node];
        const int e = row_start[node + 1];
        const int deg = e - s;
        // one coalesced load of up to 64 indices (lanes >= deg never sourced)
        int myc = 0;
        if (lane < deg) myc = col[s + lane];
        float4 acc;
        if (q == 0) {
            acc = *(const float4*)&hw[(size_t)node * 64 + 4 * t];  // self loop
        } else {
            acc.x = 0.f; acc.y = 0.f; acc.z = 0.f; acc.w = 0.f;
        }
        const int dm = min(deg, 64);   // wave-uniform
        int kk = 0;                    // wave-uniform
        // main loop: kk+q+12 <= kk+15 < dm for every quarter -> no predication
        for (; kk + 16 <= dm; kk += 16) {
            int c0 = __shfl(myc, kk + q);
            int c1 = __shfl(myc, kk + q + 4);
            int c2 = __shfl(myc, kk + q + 8);
            int c3 = __shfl(myc, kk + q + 12);
            const float4 v0 = *(const float4*)&hw[(size_t)c0 * 64 + 4 * t];
            const float4 v1 = *(const float4*)&hw[(size_t)c1 * 64 + 4 * t];
            const float4 v2 = *(const float4*)&hw[(size_t)c2 * 64 + 4 * t];
            const float4 v3 = *(const float4*)&hw[(size_t)c3 * 64 + 4 * t];
            acc.x += v0.x; acc.y += v0.y; acc.z += v0.z; acc.w += v0.w;
            acc.x += v1.x; acc.y += v1.y; acc.z += v1.z; acc.w += v1.w;
            acc.x += v2.x; acc.y += v2.y; acc.z += v2.z; acc.w += v2.w;
            acc.x += v3.x; acc.y += v3.y; acc.z += v3.z; acc.w += v3.w;
        }
        // remainder: wave-uniform loop; clamped shfl source (all lanes active),
        // predicated add. Clamped lanes load the same row -> same cache line.
        for (; kk < dm; kk += 4) {
            int idx = kk + q;
            int c = __shfl(myc, min(idx, dm - 1));
            const float4 v = *(const float4*)&hw[(size_t)c * 64 + 4 * t];
            if (idx < dm) {
                acc.x += v.x; acc.y += v.y; acc.z += v.z; acc.w += v.w;
            }
        }
        // rare fallback: degree > 64 (direct col loads, shfl-free)
        for (int j = s + 64 + q; j < e; j += 4) {
            int c = col[j];
            const float4 v = *(const float4*)&hw[(size_t)c * 64 + 4 * t];
            acc.x += v.x; acc.y += v.y; acc.z += v.z; acc.w += v.w;
        }
        acc.x += __shfl_xor(acc.x, 16); acc.y += __shfl_xor(acc.y, 16);
        acc.z += __shfl_xor(acc.z, 16); acc.w += __shfl_xor(acc.w, 16);
        acc.x += __shfl_xor(acc.x, 32); acc.y += __shfl_xor(acc.y, 32);
        acc.z += __shfl_xor(acc.z, 32); acc.w += __shfl_xor(acc.w, 32);
        if (q == 0) {
            float d = dis[node];
            float4 r;
            r.x = fmaxf(acc.x * d + b4.x, 0.f);
            r.y = fmaxf(acc.y * d + b4.y, 0.f);
            r.z = fmaxf(acc.z * d + b4.z, 0.f);
            r.w = fmaxf(acc.w * d + b4.w, 0.f);
            *(float4*)&out[(size_t)node * 64 + 4 * t] = r;
        }
    }
}

// ---------------- pool + MLP ----------------

__global__ __launch_bounds__(256) void k_pool(
        const float* __restrict__ h, const int* __restrict__ batch,
        int N, float* __restrict__ pooled) {
    __shared__ float part[4][64];
    const int g = blockIdx.x;
    const int w = threadIdx.x >> 6;
    const int lane = threadIdx.x & 63;
    int lo = 0, hi = N;
    while (lo < hi) { int mid = (lo + hi) >> 1; if (batch[mid] < g) lo = mid + 1; else hi = mid; }
    int s = lo;
    lo = 0; hi = N;
    while (lo < hi) { int mid = (lo + hi) >> 1; if (batch[mid] < g + 1) lo = mid + 1; else hi = mid; }
    int e = lo;
    float acc = 0.f;
    for (int i = s + w; i < e; i += 4) acc += h[(size_t)i * 64 + lane];
    part[w][lane] = acc;
    __syncthreads();
    if (w == 0) {
        float v = part[0][lane] + part[1][lane] + part[2][lane] + part[3][lane];
        float cnt = (float)(e - s);
        pooled[(size_t)g * 64 + lane] = v / fmaxf(cnt, 1.f);
    }
}

__global__ void k_mlp(const float* __restrict__ pooled, const float* __restrict__ Wc1,
                      const float* __restrict__ bc1, const float* __restrict__ Wc2,
                      const float* __restrict__ bc2, float* __restrict__ out) {
    __shared__ float sh[64];
    const int g = blockIdx.x;
    const int t = threadIdx.x;
    sh[t] = pooled[(size_t)g * 64 + t];
    __syncthreads();
    float part = 0.f;
    if (t < 32) {
        float z = bc1[t];
#pragma unroll
        for (int f = 0; f < 64; f++) z += sh[f] * Wc1[f * 32 + t];
        z = fmaxf(z, 0.f);
        part = z * Wc2[t];
    }
    for (int ofs = 32; ofs > 0; ofs >>= 1) part += __shfl_down(part, ofs);
    if (t == 0) out[g] = part + bc2[0];
}

// ---------------- launch ----------------

extern "C" void kernel_launch(void* const* d_in, const int* in_sizes, int n_in,
                              void* d_out, int out_size, void* d_ws, size_t ws_size,
                              hipStream_t stream) {
    const float* x     = (const float*)d_in[0];
    const int*   ei    = (const int*)d_in[1];
    const int*   batch = (const int*)d_in[2];
    const float* W1 = (const float*)d_in[3];  const float* b1 = (const float*)d_in[4];
    const float* W2 = (const float*)d_in[5];  const float* b2 = (const float*)d_in[6];
    const float* W3 = (const float*)d_in[7];  const float* b3 = (const float*)d_in[8];
    const float* Wc1 = (const float*)d_in[9];  const float* bc1 = (const float*)d_in[10];
    const float* Wc2 = (const float*)d_in[11]; const float* bc2 = (const float*)d_in[12];
    float* out = (float*)d_out;

    const int N = in_sizes[0] / 64;   // 100000
    const int E = in_sizes[1] / 2;    // 1600000
    const int G = out_size;           // 1024
    const int* src = ei;
    const int* dst = ei + E;
    const int nb = (N + 127) >> 7;    // 782 buckets
    const int ce = (E + CH - 1) / CH; // 6250 edges/chunk

    char* w = (char*)d_ws;
    auto alloc = [&](size_t bytes) -> void* {
        void* p = (void*)w;
        w += (bytes + 255) & ~(size_t)255;
        return p;
    };
    float* dis         = (float*)alloc((size_t)N * 4);
    int*   row_start   = (int*)alloc((size_t)(N + 1) * 4);
    int*   col         = (int*)alloc((size_t)E * 4);
    int*   counts      = (int*)alloc((size_t)CH * nb * 4);
    int*   loff        = (int*)alloc((size_t)CH * nb * 4);
    int*   colsum      = (int*)alloc((size_t)nb * 4);
    int*   bucket_base = (int*)alloc((size_t)(nb + 1) * 4);
    float* bufA        = (float*)alloc((size_t)N * 64 * 4);
    float* bufB        = (float*)alloc((size_t)N * 64 * 4);
    float* pooled      = (float*)alloc((size_t)G * 64 * 4);
    int*   tmp         = (int*)bufA;  // alias: CSR build finishes before layer 1
    (void)ws_size; (void)n_in;

    hipMemsetAsync(colsum, 0, (size_t)nb * 4, stream);
    k_cfill<<<CH, 256, 0, stream>>>(src, dst, counts, loff, colsum, tmp, E, ce, nb);
    k_bbase<<<1, 1024, 0, stream>>>(colsum, bucket_base, row_start, N, E, nb);
    k_pass2<<<nb, 256, 0, stream>>>(tmp, counts, loff, bucket_base, col, row_start, dis, N, ce, nb);

    // layer 1
    k_gemm_scale<<<2048, 256, 0, stream>>>(x, W1, dis, bufA, N);
    k_gather<<<4096, 256, 0, stream>>>(bufA, row_start, col, dis, b1, bufB, N);
    // layer 2
    k_gemm_scale<<<2048, 256, 0, stream>>>(bufB, W2, dis, bufA, N);
    k_gather<<<4096, 256, 0, stream>>>(bufA, row_start, col, dis, b2, bufB, N);
    // layer 3
    k_gemm_scale<<<2048, 256, 0, stream>>>(bufB, W3, dis, bufA, N);
    k_gather<<<4096, 256, 0, stream>>>(bufA, row_start, col, dis, b3, bufB, N);

    k_pool<<<G, 256, 0, stream>>>(bufB, batch, N, pooled);
    k_mlp<<<G, 64, 0, stream>>>(pooled, Wc1, bc1, Wc2, bc2, out);
}

// Round 14
// 281.352 us; speedup vs baseline: 1.3287x; 1.2126x over previous
//
#include <hip/hip_runtime.h>

#define HID 64
#define CH 256       // edge chunks (= k_cfill grid)
#define MAXNB 800    // LDS bucket-counter capacity (>= runtime nb = 782)
#define MAXCE 6400   // LDS chunk-sort capacity (>= runtime ce = 6250)
#define CAP 4096     // LDS bucket-stage capacity (>= max bucket size ~2300)

// ---------------- CSR build: chunk-local counting sort ----------------

__global__ __launch_bounds__(256) void k_cfill(
        const int* __restrict__ src, const int* __restrict__ dst,
        int* __restrict__ counts, int* __restrict__ loff,
        int* __restrict__ colsum, int* __restrict__ tmp,
        int E, int ce, int nb) {
    __shared__ int lcnt[MAXNB];
    __shared__ int lscan[MAXNB];
    __shared__ int sums[256];
    __shared__ int sorted[MAXCE];
    const int c = blockIdx.x;
    const int t = threadIdx.x;
    for (int j = t; j < nb; j += 256) lcnt[j] = 0;
    __syncthreads();
    const int s0 = c * ce, e0 = min(s0 + ce, E);
    for (int i = s0 + t; i < e0; i += 256) atomicAdd(&lcnt[dst[i] >> 7], 1);
    __syncthreads();
    for (int j = t; j < nb; j += 256) {
        int v = lcnt[j];
        counts[(size_t)c * nb + j] = v;
        if (v) atomicAdd(&colsum[j], v);
    }
    const int per = (nb + 255) >> 8;
    const int base = t * per;
    int vals[8];
    int s = 0;
    for (int k = 0; k < per; k++) {
        int f = base + k;
        int v = (f < nb) ? lcnt[f] : 0;
        vals[k] = s;
        s += v;
    }
    sums[t] = s;
    __syncthreads();
    for (int ofs = 1; ofs < 256; ofs <<= 1) {
        int v = (t >= ofs) ? sums[t - ofs] : 0;
        __syncthreads();
        sums[t] += v;
        __syncthreads();
    }
    const int carry = (t > 0) ? sums[t - 1] : 0;
    for (int k = 0; k < per; k++) {
        int f = base + k;
        if (f < nb) {
            int ex = carry + vals[k];
            lscan[f] = ex;
            loff[(size_t)c * nb + f] = ex;
        }
    }
    __syncthreads();
    for (int i = s0 + t; i < e0; i += 256) {
        int d = dst[i];
        int sv = src[i];
        int p = atomicAdd(&lscan[d >> 7], 1);
        sorted[p] = sv | ((d & 127) << 17);
    }
    __syncthreads();
    const int n = e0 - s0;
    for (int j = t; j < n; j += 256) tmp[s0 + j] = sorted[j];
}

__global__ __launch_bounds__(1024) void k_bbase(
        const int* __restrict__ colsum, int* __restrict__ bucket_base,
        int* __restrict__ row_start, int N, int E, int nb) {
    __shared__ int sums[1024];
    const int t = threadIdx.x;
    int v = (t < nb) ? colsum[t] : 0;
    sums[t] = v;
    __syncthreads();
    for (int ofs = 1; ofs < 1024; ofs <<= 1) {
        int u = (t >= ofs) ? sums[t - ofs] : 0;
        __syncthreads();
        sums[t] += u;
        __syncthreads();
    }
    if (t < nb) bucket_base[t] = sums[t] - v;
    if (t == 0) { bucket_base[nb] = E; row_start[N] = E; }
}

__global__ __launch_bounds__(256) void k_pass2(
        const int* __restrict__ tmp, const int* __restrict__ counts,
        const int* __restrict__ loff, const int* __restrict__ bucket_base,
        int* __restrict__ col, int* __restrict__ row_start,
        float* __restrict__ dis, int N, int ce, int nb) {
    __shared__ int stage[CAP];
    __shared__ int soff[256];
    __shared__ int lcnt[128];
    __shared__ int lofs[128];
    const int b = blockIdx.x;
    const int t = threadIdx.x;
    const int cnt = counts[(size_t)t * nb + b];
    const int lo  = loff[(size_t)t * nb + b];
    soff[t] = cnt;
    __syncthreads();
    for (int ofs = 1; ofs < 256; ofs <<= 1) {
        int v = (t >= ofs) ? soff[t - ofs] : 0;
        __syncthreads();
        soff[t] += v;
        __syncthreads();
    }
    const int total = soff[255];
    const int my0 = soff[t] - cnt;
    for (int k = 0; k < cnt; k++) stage[my0 + k] = tmp[t * ce + lo + k];
    if (t < 128) lcnt[t] = 0;
    __syncthreads();
    for (int i = t; i < total; i += 256) atomicAdd(&lcnt[(stage[i] >> 17) & 127], 1);
    __syncthreads();
    if (t < 128) lofs[t] = lcnt[t];
    __syncthreads();
    for (int ofs = 1; ofs < 128; ofs <<= 1) {
        int v = (t < 128 && t >= ofs) ? lofs[t - ofs] : 0;
        __syncthreads();
        if (t < 128) lofs[t] += v;
        __syncthreads();
    }
    const int base = bucket_base[b];
    if (t < 128) {
        int node = (b << 7) + t;
        int ex = lofs[t] - lcnt[t];
        if (node < N) {
            row_start[node] = base + ex;
            dis[node] = rsqrtf((float)(lcnt[t] + 1));
        }
        lcnt[t] = ex;
    }
    __syncthreads();
    for (int i = t; i < total; i += 256) {
        int v = stage[i];
        int d = (v >> 17) & 127;
        int p = atomicAdd(&lcnt[d], 1);
        col[base + p] = v & 0x1FFFF;
    }
}

// ---------------- per-layer compute ----------------

// hw[n,f] = (X[n,:] @ W[:,f]) * dis[n], stored bf16 (RNE). wcol in VGPRs.
__global__ __launch_bounds__(256) void k_gemm_scale(
        const float* __restrict__ X, const float* __restrict__ W,
        const float* __restrict__ dis, unsigned short* __restrict__ out, int N) {
    __shared__ float xsh[4][64];
    const int wave = threadIdx.x >> 6;
    const int lane = threadIdx.x & 63;
    float wcol[64];
#pragma unroll
    for (int k = 0; k < 64; k++) wcol[k] = W[k * 64 + lane];

    const int nwaves = gridDim.x * 4;
    for (int node = blockIdx.x * 4 + wave; node < N; node += nwaves) {
        xsh[wave][lane] = X[(size_t)node * 64 + lane];
        asm volatile("s_waitcnt lgkmcnt(0)" ::: "memory");
        float acc = 0.f;
#pragma unroll
        for (int k = 0; k < 64; k += 4) {
            float4 xv = *(const float4*)&xsh[wave][k];
            acc += xv.x * wcol[k]     + xv.y * wcol[k + 1]
                 + xv.z * wcol[k + 2] + xv.w * wcol[k + 3];
        }
        unsigned u = __float_as_uint(acc * dis[node]);
        u += 0x7fffu + ((u >> 16) & 1u);   // RNE to bf16
        out[(size_t)node * 64 + lane] = (unsigned short)(u >> 16);
    }
}

__device__ __forceinline__ float4 bf4_to_f4(uint2 v) {
    float4 r;
    r.x = __uint_as_float(v.x << 16);
    r.y = __uint_as_float(v.x & 0xffff0000u);
    r.z = __uint_as_float(v.y << 16);
    r.w = __uint_as_float(v.y & 0xffff0000u);
    return r;
}

// h[n,f] = relu( dis[n] * ( hw[n,f] + sum_{e} hw[col[e],f] ) + b[f] ), hw bf16.
// Coalesced col load -> shfl distribution (wave-uniform control flow, R12/R13
// lesson: shfl source lanes must be exec-active). 4 independent 8 B row loads
// per quarter in flight.
__global__ __launch_bounds__(256) void k_gather(
        const unsigned short* __restrict__ hw, const int* __restrict__ row_start,
        const int* __restrict__ col, const float* __restrict__ dis,
        const float* __restrict__ bias, float* __restrict__ out, int N) {
    const int wave = threadIdx.x >> 6;
    const int lane = threadIdx.x & 63;
    const int q = lane >> 4;
    const int t = lane & 15;
    const float4 b4 = *(const float4*)&bias[4 * t];
    const int nwaves = gridDim.x * 4;
    for (int node = blockIdx.x * 4 + wave; node < N; node += nwaves) {
        const int s = row_start[node];
        const int e = row_start[node + 1];
        const int deg = e - s;
        int myc = 0;
        if (lane < deg) myc = col[s + lane];
        float4 acc;
        if (q == 0) {
            acc = bf4_to_f4(*(const uint2*)&hw[(size_t)node * 64 + 4 * t]);  // self loop
        } else {
            acc.x = 0.f; acc.y = 0.f; acc.z = 0.f; acc.w = 0.f;
        }
        const int dm = min(deg, 64);   // wave-uniform
        int kk = 0;
        for (; kk + 16 <= dm; kk += 16) {
            int c0 = __shfl(myc, kk + q);
            int c1 = __shfl(myc, kk + q + 4);
            int c2 = __shfl(myc, kk + q + 8);
            int c3 = __shfl(myc, kk + q + 12);
            const uint2 w0 = *(const uint2*)&hw[(size_t)c0 * 64 + 4 * t];
            const uint2 w1 = *(const uint2*)&hw[(size_t)c1 * 64 + 4 * t];
            const uint2 w2 = *(const uint2*)&hw[(size_t)c2 * 64 + 4 * t];
            const uint2 w3 = *(const uint2*)&hw[(size_t)c3 * 64 + 4 * t];
            float4 v;
            v = bf4_to_f4(w0); acc.x += v.x; acc.y += v.y; acc.z += v.z; acc.w += v.w;
            v = bf4_to_f4(w1); acc.x += v.x; acc.y += v.y; acc.z += v.z; acc.w += v.w;
            v = bf4_to_f4(w2); acc.x += v.x; acc.y += v.y; acc.z += v.z; acc.w += v.w;
            v = bf4_to_f4(w3); acc.x += v.x; acc.y += v.y; acc.z += v.z; acc.w += v.w;
        }
        for (; kk < dm; kk += 4) {
            int idx = kk + q;
            int c = __shfl(myc, min(idx, dm - 1));
            const uint2 wv = *(const uint2*)&hw[(size_t)c * 64 + 4 * t];
            if (idx < dm) {
                float4 v = bf4_to_f4(wv);
                acc.x += v.x; acc.y += v.y; acc.z += v.z; acc.w += v.w;
            }
        }
        for (int j = s + 64 + q; j < e; j += 4) {   // rare: degree > 64
            int c = col[j];
            float4 v = bf4_to_f4(*(const uint2*)&hw[(size_t)c * 64 + 4 * t]);
            acc.x += v.x; acc.y += v.y; acc.z += v.z; acc.w += v.w;
        }
        acc.x += __shfl_xor(acc.x, 16); acc.y += __shfl_xor(acc.y, 16);
        acc.z += __shfl_xor(acc.z, 16); acc.w += __shfl_xor(acc.w, 16);
        acc.x += __shfl_xor(acc.x, 32); acc.y += __shfl_xor(acc.y, 32);
        acc.z += __shfl_xor(acc.z, 32); acc.w += __shfl_xor(acc.w, 32);
        if (q == 0) {
            float d = dis[node];
            float4 r;
            r.x = fmaxf(acc.x * d + b4.x, 0.f);
            r.y = fmaxf(acc.y * d + b4.y, 0.f);
            r.z = fmaxf(acc.z * d + b4.z, 0.f);
            r.w = fmaxf(acc.w * d + b4.w, 0.f);
            *(float4*)&out[(size_t)node * 64 + 4 * t] = r;
        }
    }
}

// ---------------- pool + MLP ----------------

__global__ __launch_bounds__(256) void k_pool(
        const float* __restrict__ h, const int* __restrict__ batch,
        int N, float* __restrict__ pooled) {
    __shared__ float part[4][64];
    const int g = blockIdx.x;
    const int w = threadIdx.x >> 6;
    const int lane = threadIdx.x & 63;
    int lo = 0, hi = N;
    while (lo < hi) { int mid = (lo + hi) >> 1; if (batch[mid] < g) lo = mid + 1; else hi = mid; }
    int s = lo;
    lo = 0; hi = N;
    while (lo < hi) { int mid = (lo + hi) >> 1; if (batch[mid] < g + 1) lo = mid + 1; else hi = mid; }
    int e = lo;
    float acc = 0.f;
    for (int i = s + w; i < e; i += 4) acc += h[(size_t)i * 64 + lane];
    part[w][lane] = acc;
    __syncthreads();
    if (w == 0) {
        float v = part[0][lane] + part[1][lane] + part[2][lane] + part[3][lane];
        float cnt = (float)(e - s);
        pooled[(size_t)g * 64 + lane] = v / fmaxf(cnt, 1.f);
    }
}

__global__ void k_mlp(const float* __restrict__ pooled, const float* __restrict__ Wc1,
                      const float* __restrict__ bc1, const float* __restrict__ Wc2,
                      const float* __restrict__ bc2, float* __restrict__ out) {
    __shared__ float sh[64];
    const int g = blockIdx.x;
    const int t = threadIdx.x;
    sh[t] = pooled[(size_t)g * 64 + t];
    __syncthreads();
    float part = 0.f;
    if (t < 32) {
        float z = bc1[t];
#pragma unroll
        for (int f = 0; f < 64; f++) z += sh[f] * Wc1[f * 32 + t];
        z = fmaxf(z, 0.f);
        part = z * Wc2[t];
    }
    for (int ofs = 32; ofs > 0; ofs >>= 1) part += __shfl_down(part, ofs);
    if (t == 0) out[g] = part + bc2[0];
}

// ---------------- launch ----------------

extern "C" void kernel_launch(void* const* d_in, const int* in_sizes, int n_in,
                              void* d_out, int out_size, void* d_ws, size_t ws_size,
                              hipStream_t stream) {
    const float* x     = (const float*)d_in[0];
    const int*   ei    = (const int*)d_in[1];
    const int*   batch = (const int*)d_in[2];
    const float* W1 = (const float*)d_in[3];  const float* b1 = (const float*)d_in[4];
    const float* W2 = (const float*)d_in[5];  const float* b2 = (const float*)d_in[6];
    const float* W3 = (const float*)d_in[7];  const float* b3 = (const float*)d_in[8];
    const float* Wc1 = (const float*)d_in[9];  const float* bc1 = (const float*)d_in[10];
    const float* Wc2 = (const float*)d_in[11]; const float* bc2 = (const float*)d_in[12];
    float* out = (float*)d_out;

    const int N = in_sizes[0] / 64;   // 100000
    const int E = in_sizes[1] / 2;    // 1600000
    const int G = out_size;           // 1024
    const int* src = ei;
    const int* dst = ei + E;
    const int nb = (N + 127) >> 7;    // 782 buckets
    const int ce = (E + CH - 1) / CH; // 6250 edges/chunk

    char* w = (char*)d_ws;
    auto alloc = [&](size_t bytes) -> void* {
        void* p = (void*)w;
        w += (bytes + 255) & ~(size_t)255;
        return p;
    };
    float* dis         = (float*)alloc((size_t)N * 4);
    int*   row_start   = (int*)alloc((size_t)(N + 1) * 4);
    int*   col         = (int*)alloc((size_t)E * 4);
    int*   counts      = (int*)alloc((size_t)CH * nb * 4);
    int*   loff        = (int*)alloc((size_t)CH * nb * 4);
    int*   colsum      = (int*)alloc((size_t)nb * 4);
    int*   bucket_base = (int*)alloc((size_t)(nb + 1) * 4);
    unsigned short* hwb = (unsigned short*)alloc((size_t)N * 64 * 2);  // bf16 hw
    float* hbuf        = (float*)alloc((size_t)N * 64 * 4);            // f32 h
    float* pooled      = (float*)alloc((size_t)G * 64 * 4);
    int*   tmp         = (int*)hbuf;  // alias: CSR build finishes before layer 1
    (void)ws_size; (void)n_in;

    hipMemsetAsync(colsum, 0, (size_t)nb * 4, stream);
    k_cfill<<<CH, 256, 0, stream>>>(src, dst, counts, loff, colsum, tmp, E, ce, nb);
    k_bbase<<<1, 1024, 0, stream>>>(colsum, bucket_base, row_start, N, E, nb);
    k_pass2<<<nb, 256, 0, stream>>>(tmp, counts, loff, bucket_base, col, row_start, dis, N, ce, nb);

    // layer 1
    k_gemm_scale<<<2048, 256, 0, stream>>>(x, W1, dis, hwb, N);
    k_gather<<<4096, 256, 0, stream>>>(hwb, row_start, col, dis, b1, hbuf, N);
    // layer 2
    k_gemm_scale<<<2048, 256, 0, stream>>>(hbuf, W2, dis, hwb, N);
    k_gather<<<4096, 256, 0, stream>>>(hwb, row_start, col, dis, b2, hbuf, N);
    // layer 3
    k_gemm_scale<<<2048, 256, 0, stream>>>(hbuf, W3, dis, hwb, N);
    k_gather<<<4096, 256, 0, stream>>>(hwb, row_start, col, dis, b3, hbuf, N);

    k_pool<<<G, 256, 0, stream>>>(hbuf, batch, N, pooled);
    k_mlp<<<G, 64, 0, stream>>>(pooled, Wc1, bc1, Wc2, bc2, out);
}